// Round 2
// baseline (211.370 us; speedup 1.0000x reference)
//
#include <hip/hip_runtime.h>
#include <hip/hip_bf16.h>

constexpr int NN = 1024;   // nodes
constexpr int DD = 128;    // NODE_DIM == HID
constexpr int EDIM = 32;   // EDGE_DIM
constexpr int NR = 16;     // NREL

using short4v = __attribute__((ext_vector_type(4))) short;
using short8v = __attribute__((ext_vector_type(8))) short;
using f32x4   = __attribute__((ext_vector_type(4))) float;

__device__ __forceinline__ short f2bf(float x) {
  __hip_bfloat16 h = __float2bfloat16(x);   // RNE
  return __builtin_bit_cast(short, h);
}

// ---------------- K1: rsinv[i] = 1/(rowsum(adj[i]) + 1e-6) ----------------
__global__ __launch_bounds__(256) void k_rowsum(const float* __restrict__ adj,
                                                float* __restrict__ rsinv) {
  int i = blockIdx.x, t = threadIdx.x;
  const float4* row = (const float4*)(adj + (size_t)i * NN);
  float4 v = row[t];                       // 256 threads * 4 = 1024
  float s = v.x + v.y + v.z + v.w;
  #pragma unroll
  for (int off = 32; off > 0; off >>= 1) s += __shfl_down(s, off, 64);
  __shared__ float red[4];
  if ((t & 63) == 0) red[t >> 6] = s;
  __syncthreads();
  if (t == 0) rsinv[i] = 1.0f / (red[0] + red[1] + red[2] + red[3] + 1e-6f);
}

// ---------------- K2a: partial[kc][i][h] = sum_{k in chunk} adj[i][k]*X[k][h] ----------------
// grid = 64 i-tiles * 8 k-chunks = 512 blocks, 256 threads
__global__ __launch_bounds__(256) void k_adjgemm(const float* __restrict__ adj,
                                                 const float* __restrict__ X,
                                                 float* __restrict__ part) {
  __shared__ float sadj[16][128];          // 8 KB
  int t = threadIdx.x;
  int ic = blockIdx.x & 63, kc = blockIdx.x >> 6;
  int i0 = ic * 16, k0 = kc * 128;
  {
    int il = t >> 4;                       // 0..15
    int kl = (t & 15) * 8;                 // 0..120
    const float4* src = (const float4*)(adj + (size_t)(i0 + il) * NN + k0 + kl);
    *(float4*)&sadj[il][kl]     = src[0];
    *(float4*)&sadj[il][kl + 4] = src[1];
  }
  __syncthreads();
  int h = t & 127, ii = t >> 7;            // ii in {0,1}
  float acc[8] = {0,0,0,0,0,0,0,0};
  for (int k = 0; k < 128; k += 4) {
    float x0 = X[(size_t)(k0 + k) * DD + h];
    float x1 = X[(size_t)(k0 + k + 1) * DD + h];
    float x2 = X[(size_t)(k0 + k + 2) * DD + h];
    float x3 = X[(size_t)(k0 + k + 3) * DD + h];
    #pragma unroll
    for (int m = 0; m < 8; ++m) {
      int il = ii + m * 2;
      float4 a = *(const float4*)&sadj[il][k];   // broadcast across the wave
      acc[m] += a.x * x0 + a.y * x1 + a.z * x2 + a.w * x3;
    }
  }
  #pragma unroll
  for (int m = 0; m < 8; ++m)
    part[((size_t)kc * NN + (i0 + ii + m * 2)) * DD + h] = acc[m];
}

// ---------------- K3/K5 (fused aggfin+dense): ----------------
// agg[i][h] = rsinv[i]*sum_kc part[kc][i][h]  (into LDS)
// out[i][h] = relu( X[i]@W[h][0:128] + agg[i]@W[h][128:256] + b[h] ), W ld=256
__global__ __launch_bounds__(256) void k_dense2f(const float* __restrict__ X,
                                                 const float* __restrict__ part,
                                                 const float* __restrict__ rsinv,
                                                 const float* __restrict__ W,
                                                 const float* __restrict__ b,
                                                 float* __restrict__ out) {
  __shared__ float sagg[2][128];
  int t = threadIdx.x;
  int ig = t >> 7, h = t & 127;
  int i = blockIdx.x * 2 + ig;
  {
    float s = 0.f;
    #pragma unroll
    for (int kc = 0; kc < 8; ++kc) s += part[(size_t)kc * NN * DD + (size_t)i * DD + h];
    sagg[ig][h] = s * rsinv[i];
  }
  __syncthreads();
  const float4* xr = (const float4*)(X + (size_t)i * DD);
  const float4* ar = (const float4*)(&sagg[ig][0]);
  const float4* w1 = (const float4*)(W + (size_t)h * 256);
  const float4* w2 = (const float4*)(W + (size_t)h * 256 + DD);
  float acc = b[h];
  #pragma unroll 8
  for (int k = 0; k < 32; ++k) {
    float4 x = xr[k], w = w1[k];
    acc += x.x * w.x + x.y * w.y + x.z * w.z + x.w * w.w;
  }
  #pragma unroll 8
  for (int k = 0; k < 32; ++k) {
    float4 y = ar[k], w = w2[k];
    acc += y.x * w.x + y.y * w.y + y.z * w.z + y.w * w.w;
  }
  out[(size_t)i * DD + h] = fmaxf(acc, 0.f);
}

// ---------------- K6: Aib[i][h] = h2[i]@Wa[h] + b_c1[h];  Bmat[i][h] = h2[i]@Wb[h] ----------------
__global__ __launch_bounds__(256) void k_ab(const float* __restrict__ h2,
                                            const float* __restrict__ Wc1,
                                            const float* __restrict__ bc1,
                                            float* __restrict__ Aib,
                                            float* __restrict__ Bmat) {
  int t = threadIdx.x;
  int i = blockIdx.x * 2 + (t >> 7), h = t & 127;
  const float4* xr = (const float4*)(h2 + (size_t)i * DD);
  const float4* wa = (const float4*)(Wc1 + (size_t)h * 288);
  const float4* wb = (const float4*)(Wc1 + (size_t)h * 288 + 128);
  float aa = bc1[h], bb = 0.f;
  #pragma unroll 8
  for (int k = 0; k < 32; ++k) {
    float4 x = xr[k];
    float4 a = wa[k], b2 = wb[k];
    aa += x.x * a.x + x.y * a.y + x.z * a.z + x.w * a.w;
    bb += x.x * b2.x + x.y * b2.y + x.z * b2.z + x.w * b2.w;
  }
  Aib[(size_t)i * DD + h] = aa;
  Bmat[(size_t)i * DD + h] = bb;
}

// ---------------- K7: fused edge stage (v2: 1-wave blocks, prefetch, dbuf LDS, fixed swizzle)
// pre[i,j,h] = edge[i,j,:]@We[h,:]ᵀ + Aib[i,h] + Bmat[j,h]   (b_c1 folded in Aib)
// out[i,j,r] = (i==j) ? 0 : relu(pre)@Wc2[r,:]ᵀ + b_c2[r]
// grid: blockIdx = iq*16 + jb; wave covers i = iq*4..+3, j = jb*64..+63 (16 iterations of 16 pairs)
__global__ __launch_bounds__(64, 3) void k_edge(const float* __restrict__ edge,
                                                const float* __restrict__ Wc1,
                                                const float* __restrict__ Wc2,
                                                const float* __restrict__ bc2,
                                                const float* __restrict__ Aib,
                                                const float* __restrict__ Bmat,
                                                float* __restrict__ out) {
  __shared__ __align__(16) char plds[2][4096];  // double-buffered 16x128 bf16 P-tile
  int lane = threadIdx.x;
  int c = lane & 15, g = lane >> 4;
  int iq = blockIdx.x >> 4;                     // 0..255
  int jb = blockIdx.x & 15;                     // 0..15
  int rowbase = c * 256;
  int swz = (c & 3) << 5;                       // bank bits 5-6 <- pair entropy

  // Preload We fragments: A1[m=c][k=8g+j] = Wc1[16n+c][256 + 8g+j]
  short8v weF[8];
  #pragma unroll
  for (int n = 0; n < 8; ++n) {
    const float* p = Wc1 + (size_t)(16 * n + c) * 288 + 256 + 8 * g;
    float4 f0 = *(const float4*)p;
    float4 f1 = *(const float4*)(p + 4);
    short8v s;
    s[0]=f2bf(f0.x); s[1]=f2bf(f0.y); s[2]=f2bf(f0.z); s[3]=f2bf(f0.w);
    s[4]=f2bf(f1.x); s[5]=f2bf(f1.y); s[6]=f2bf(f1.z); s[7]=f2bf(f1.w);
    weF[n] = s;
  }
  // Preload Wc2 fragments: A2[m=c][k=32kk+8g+j] = Wc2[c][32kk+8g+j]
  short8v wcF[4];
  #pragma unroll
  for (int kk = 0; kk < 4; ++kk) {
    const float* p = Wc2 + (size_t)c * DD + 32 * kk + 8 * g;
    float4 f0 = *(const float4*)p;
    float4 f1 = *(const float4*)(p + 4);
    short8v s;
    s[0]=f2bf(f0.x); s[1]=f2bf(f0.y); s[2]=f2bf(f0.z); s[3]=f2bf(f0.w);
    s[4]=f2bf(f1.x); s[5]=f2bf(f1.y); s[6]=f2bf(f1.z); s[7]=f2bf(f1.w);
    wcF[kk] = s;
  }
  float4 bc2v = *(const float4*)(bc2 + 4 * g);

  // prefetch edge tile for it=0
  float4 pe0, pe1;
  {
    const float* p = edge + ((size_t)(iq * 4) * NN + jb * 64 + c) * EDIM + 8 * g;
    pe0 = *(const float4*)p;
    pe1 = *(const float4*)(p + 4);
  }

  auto body = [&](int it, char* buf) {
    float4 e0 = pe0, e1 = pe1;
    // issue next edge loads (distance-1 prefetch; it=15 wraps to 0, harmless)
    {
      int itn = (it + 1) & 15;
      const float* p = edge + ((size_t)(iq * 4 + (itn >> 2)) * NN + jb * 64 + (itn & 3) * 16 + c) * EDIM + 8 * g;
      pe0 = *(const float4*)p;
      pe1 = *(const float4*)(p + 4);
    }
    short8v ef;
    ef[0]=f2bf(e0.x); ef[1]=f2bf(e0.y); ef[2]=f2bf(e0.z); ef[3]=f2bf(e0.w);
    ef[4]=f2bf(e1.x); ef[5]=f2bf(e1.y); ef[6]=f2bf(e1.z); ef[7]=f2bf(e1.w);

    int i = iq * 4 + (it >> 2);
    int j = jb * 64 + (it & 3) * 16 + c;
    const float* ap = Aib + (size_t)i * DD + 4 * g;
    const float* bp = Bmat + (size_t)j * DD + 4 * g;
    f32x4 z = {0.f, 0.f, 0.f, 0.f};

    // GEMM1 in two halves of 4 h-tiles to cap live registers
    #pragma unroll
    for (int hlf = 0; hlf < 2; ++hlf) {
      f32x4 acc[4];
      #pragma unroll
      for (int q = 0; q < 4; ++q)
        acc[q] = __builtin_amdgcn_mfma_f32_16x16x32_bf16(weF[4 * hlf + q], ef, z, 0, 0, 0);
      #pragma unroll
      for (int q = 0; q < 4; ++q) {
        int n = 4 * hlf + q;
        float4 av = *(const float4*)(ap + 16 * n);
        float4 bv = *(const float4*)(bp + 16 * n);
        short4v pk;
        pk[0] = f2bf(fmaxf(acc[q][0] + av.x + bv.x, 0.f));
        pk[1] = f2bf(fmaxf(acc[q][1] + av.y + bv.y, 0.f));
        pk[2] = f2bf(fmaxf(acc[q][2] + av.z + bv.z, 0.f));
        pk[3] = f2bf(fmaxf(acc[q][3] + av.w + bv.w, 0.f));
        *(short4v*)(buf + rowbase + ((32 * n + 8 * g) ^ swz)) = pk;
      }
    }
    // GEMM2: D2[rel=4g+r][pair=c]; C-in = b_c2
    f32x4 acc2;
    acc2[0] = bc2v.x; acc2[1] = bc2v.y; acc2[2] = bc2v.z; acc2[3] = bc2v.w;
    #pragma unroll
    for (int kk = 0; kk < 4; ++kk) {
      short8v pb = *(short8v*)(buf + rowbase + ((64 * kk + 16 * g) ^ swz));
      acc2 = __builtin_amdgcn_mfma_f32_16x16x32_bf16(wcF[kk], pb, acc2, 0, 0, 0);
    }
    bool diag = (j == i);
    float4 o;
    o.x = diag ? 0.f : acc2[0];
    o.y = diag ? 0.f : acc2[1];
    o.z = diag ? 0.f : acc2[2];
    o.w = diag ? 0.f : acc2[3];
    *(float4*)(out + ((size_t)i * NN + j) * NR + 4 * g) = o;
  };

  char* pl0 = (char*)plds[0];
  char* pl1 = (char*)plds[1];
  for (int it2 = 0; it2 < 8; ++it2) {
    body(2 * it2,     pl0);
    body(2 * it2 + 1, pl1);
  }
}

extern "C" void kernel_launch(void* const* d_in, const int* in_sizes, int n_in,
                              void* d_out, int out_size, void* d_ws, size_t ws_size,
                              hipStream_t stream) {
  const float* node_feat = (const float*)d_in[0];
  const float* edge_feat = (const float*)d_in[1];
  const float* adj  = (const float*)d_in[2];
  const float* W_g1 = (const float*)d_in[3];
  const float* b_g1 = (const float*)d_in[4];
  const float* W_g2 = (const float*)d_in[5];
  const float* b_g2 = (const float*)d_in[6];
  const float* W_c1 = (const float*)d_in[7];
  const float* b_c1 = (const float*)d_in[8];
  const float* W_c2 = (const float*)d_in[9];
  const float* b_c2 = (const float*)d_in[10];
  float* out = (float*)d_out;

  float* ws    = (float*)d_ws;
  float* rsinv = ws;                        // 1024
  float* part  = ws + 1024;                 // 8*1024*128 = 1048576
  float* h1    = part + 8 * NN * DD;        // 131072
  float* h2    = h1 + NN * DD;              // 131072
  float* Aib   = h2 + NN * DD;              // 131072
  float* Bmat  = Aib + NN * DD;             // 131072   (total ~6.3 MB)

  k_rowsum<<<NN, 256, 0, stream>>>(adj, rsinv);
  // layer 1
  k_adjgemm<<<512, 256, 0, stream>>>(adj, node_feat, part);
  k_dense2f<<<512, 256, 0, stream>>>(node_feat, part, rsinv, W_g1, b_g1, h1);
  // layer 2
  k_adjgemm<<<512, 256, 0, stream>>>(adj, h1, part);
  k_dense2f<<<512, 256, 0, stream>>>(h1, part, rsinv, W_g2, b_g2, h2);
  // head precompute
  k_ab<<<512, 256, 0, stream>>>(h2, W_c1, b_c1, Aib, Bmat);
  // fused edge stage
  k_edge<<<4096, 64, 0, stream>>>(edge_feat, W_c1, W_c2, b_c2, Aib, Bmat, out);
}

// Round 3
// 154.922 us; speedup vs baseline: 1.3644x; 1.3644x over previous
//
#include <hip/hip_runtime.h>
#include <hip/hip_bf16.h>

constexpr int NN = 1024;   // nodes
constexpr int DD = 128;    // NODE_DIM == HID
constexpr int EDIM = 32;   // EDGE_DIM
constexpr int NR = 16;     // NREL

using short4v = __attribute__((ext_vector_type(4))) short;
using short8v = __attribute__((ext_vector_type(8))) short;
using f32x4   = __attribute__((ext_vector_type(4))) float;

__device__ __forceinline__ short f2bf(float x) {
  __hip_bfloat16 h = __float2bfloat16(x);   // RNE
  return __builtin_bit_cast(short, h);
}

// ---------------- K1: rsinv[i] = 1/(rowsum(adj[i]) + 1e-6) ----------------
__global__ __launch_bounds__(256) void k_rowsum(const float* __restrict__ adj,
                                                float* __restrict__ rsinv) {
  int i = blockIdx.x, t = threadIdx.x;
  const float4* row = (const float4*)(adj + (size_t)i * NN);
  float4 v = row[t];                       // 256 threads * 4 = 1024
  float s = v.x + v.y + v.z + v.w;
  #pragma unroll
  for (int off = 32; off > 0; off >>= 1) s += __shfl_down(s, off, 64);
  __shared__ float red[4];
  if ((t & 63) == 0) red[t >> 6] = s;
  __syncthreads();
  if (t == 0) rsinv[i] = 1.0f / (red[0] + red[1] + red[2] + red[3] + 1e-6f);
}

// ---------------- K2a: partial[kc][i][h] = sum_{k in chunk} adj[i][k]*X[k][h] ----------------
__global__ __launch_bounds__(256) void k_adjgemm(const float* __restrict__ adj,
                                                 const float* __restrict__ X,
                                                 float* __restrict__ part) {
  __shared__ float sadj[16][128];          // 8 KB
  int t = threadIdx.x;
  int ic = blockIdx.x & 63, kc = blockIdx.x >> 6;
  int i0 = ic * 16, k0 = kc * 128;
  {
    int il = t >> 4;                       // 0..15
    int kl = (t & 15) * 8;                 // 0..120
    const float4* src = (const float4*)(adj + (size_t)(i0 + il) * NN + k0 + kl);
    *(float4*)&sadj[il][kl]     = src[0];
    *(float4*)&sadj[il][kl + 4] = src[1];
  }
  __syncthreads();
  int h = t & 127, ii = t >> 7;            // ii in {0,1}
  float acc[8] = {0,0,0,0,0,0,0,0};
  for (int k = 0; k < 128; k += 4) {
    float x0 = X[(size_t)(k0 + k) * DD + h];
    float x1 = X[(size_t)(k0 + k + 1) * DD + h];
    float x2 = X[(size_t)(k0 + k + 2) * DD + h];
    float x3 = X[(size_t)(k0 + k + 3) * DD + h];
    #pragma unroll
    for (int m = 0; m < 8; ++m) {
      int il = ii + m * 2;
      float4 a = *(const float4*)&sadj[il][k];   // broadcast across the wave
      acc[m] += a.x * x0 + a.y * x1 + a.z * x2 + a.w * x3;
    }
  }
  #pragma unroll
  for (int m = 0; m < 8; ++m)
    part[((size_t)kc * NN + (i0 + ii + m * 2)) * DD + h] = acc[m];
}

// ---------------- K3/K5 (fused aggfin+dense) ----------------
__global__ __launch_bounds__(256) void k_dense2f(const float* __restrict__ X,
                                                 const float* __restrict__ part,
                                                 const float* __restrict__ rsinv,
                                                 const float* __restrict__ W,
                                                 const float* __restrict__ b,
                                                 float* __restrict__ out) {
  __shared__ float sagg[2][128];
  int t = threadIdx.x;
  int ig = t >> 7, h = t & 127;
  int i = blockIdx.x * 2 + ig;
  {
    float s = 0.f;
    #pragma unroll
    for (int kc = 0; kc < 8; ++kc) s += part[(size_t)kc * NN * DD + (size_t)i * DD + h];
    sagg[ig][h] = s * rsinv[i];
  }
  __syncthreads();
  const float4* xr = (const float4*)(X + (size_t)i * DD);
  const float4* ar = (const float4*)(&sagg[ig][0]);
  const float4* w1 = (const float4*)(W + (size_t)h * 256);
  const float4* w2 = (const float4*)(W + (size_t)h * 256 + DD);
  float acc = b[h];
  #pragma unroll 8
  for (int k = 0; k < 32; ++k) {
    float4 x = xr[k], w = w1[k];
    acc += x.x * w.x + x.y * w.y + x.z * w.z + x.w * w.w;
  }
  #pragma unroll 8
  for (int k = 0; k < 32; ++k) {
    float4 y = ar[k], w = w2[k];
    acc += y.x * w.x + y.y * w.y + y.z * w.z + y.w * w.w;
  }
  out[(size_t)i * DD + h] = fmaxf(acc, 0.f);
}

// ---------------- K6: Aib/Bmat precompute ----------------
__global__ __launch_bounds__(256) void k_ab(const float* __restrict__ h2,
                                            const float* __restrict__ Wc1,
                                            const float* __restrict__ bc1,
                                            float* __restrict__ Aib,
                                            float* __restrict__ Bmat) {
  int t = threadIdx.x;
  int i = blockIdx.x * 2 + (t >> 7), h = t & 127;
  const float4* xr = (const float4*)(h2 + (size_t)i * DD);
  const float4* wa = (const float4*)(Wc1 + (size_t)h * 288);
  const float4* wb = (const float4*)(Wc1 + (size_t)h * 288 + 128);
  float aa = bc1[h], bb = 0.f;
  #pragma unroll 8
  for (int k = 0; k < 32; ++k) {
    float4 x = xr[k];
    float4 a = wa[k], b2 = wb[k];
    aa += x.x * a.x + x.y * a.y + x.z * a.z + x.w * a.w;
    bb += x.x * b2.x + x.y * b2.y + x.z * b2.z + x.w * b2.w;
  }
  Aib[(size_t)i * DD + h] = aa;
  Bmat[(size_t)i * DD + h] = bb;
}

// ---------------- K7: fused edge stage (v3) ----------------
// Wave owns j-tile (16 j) x 8 i's. C-in = Aib[i]+Bmat[j]. P transposed via
// derived conflict-free LDS layout: chunk(kk,g,c) 16B = P[32kk+8g+0..7][c].
// writer lane (c,gs), reg n: addr = (n>>1)*1024 + (2(n&1)+(gs>>1))*256 + c*16 + (gs&1)*8
// reader lane (c,g), kk:    addr = kk*1024 + g*256 + c*16   (lane-linear b128)
__global__ __launch_bounds__(256, 3) void k_edge(const float* __restrict__ edge,
                                                 const float* __restrict__ Wc1,
                                                 const float* __restrict__ Wc2,
                                                 const float* __restrict__ bc2,
                                                 const float* __restrict__ Aib,
                                                 const float* __restrict__ Bmat,
                                                 float* __restrict__ out) {
  __shared__ __align__(16) char plds[4][2][4096];   // 32 KB: per-wave dbuf P-tiles
  int tid = threadIdx.x;
  int w = tid >> 6, lane = tid & 63;
  int c = lane & 15, g = lane >> 4;
  int ig = blockIdx.x >> 4;                 // 0..127 -> 8 i's
  int jg = blockIdx.x & 15;                 // 0..15
  int i0 = ig * 8;
  int j  = jg * 64 + w * 16 + c;            // this lane's pair column

  // ---- per-wave persistent state ----
  // We fragments: A1[m=c][k=8g+jj] = Wc1[16n+c][256+8g+jj]
  short8v weF[8];
  #pragma unroll
  for (int n = 0; n < 8; ++n) {
    const float* p = Wc1 + (size_t)(16 * n + c) * 288 + 256 + 8 * g;
    float4 f0 = *(const float4*)p;
    float4 f1 = *(const float4*)(p + 4);
    short8v s;
    s[0]=f2bf(f0.x); s[1]=f2bf(f0.y); s[2]=f2bf(f0.z); s[3]=f2bf(f0.w);
    s[4]=f2bf(f1.x); s[5]=f2bf(f1.y); s[6]=f2bf(f1.z); s[7]=f2bf(f1.w);
    weF[n] = s;
  }
  // Wc2 fragments: A2[m=c][k=32kk+8g+jj]
  short8v wcF[4];
  #pragma unroll
  for (int kk = 0; kk < 4; ++kk) {
    const float* p = Wc2 + (size_t)c * DD + 32 * kk + 8 * g;
    float4 f0 = *(const float4*)p;
    float4 f1 = *(const float4*)(p + 4);
    short8v s;
    s[0]=f2bf(f0.x); s[1]=f2bf(f0.y); s[2]=f2bf(f0.z); s[3]=f2bf(f0.w);
    s[4]=f2bf(f1.x); s[5]=f2bf(f1.y); s[6]=f2bf(f1.z); s[7]=f2bf(f1.w);
    wcF[kk] = s;
  }
  float4 bc2v = *(const float4*)(bc2 + 4 * g);
  // Bmat for this lane's j, reused across all 8 i's
  float4 bjv[8];
  #pragma unroll
  for (int n = 0; n < 8; ++n)
    bjv[n] = *(const float4*)(Bmat + (size_t)j * DD + 16 * n + 4 * g);

  char* wbase = &plds[w][0][0];
  int wroff = (c << 4) + ((g & 1) << 3) + ((g >> 1) << 8);  // lane part of write addr
  int rdoff = (g << 8) + (c << 4);                          // lane part of read addr

  // prefetch edge for t=0
  float4 pe0, pe1;
  {
    const float* p = edge + ((size_t)i0 * NN + j) * EDIM + 8 * g;
    pe0 = *(const float4*)p;
    pe1 = *(const float4*)(p + 4);
  }

  for (int t = 0; t < 8; ++t) {
    float4 e0 = pe0, e1 = pe1;
    {   // issue next prefetch immediately (t=7 wraps; harmless reload)
      int tn = (t + 1) & 7;
      const float* p = edge + ((size_t)(i0 + tn) * NN + j) * EDIM + 8 * g;
      pe0 = *(const float4*)p;
      pe1 = *(const float4*)(p + 4);
    }
    short8v ef;
    ef[0]=f2bf(e0.x); ef[1]=f2bf(e0.y); ef[2]=f2bf(e0.z); ef[3]=f2bf(e0.w);
    ef[4]=f2bf(e1.x); ef[5]=f2bf(e1.y); ef[6]=f2bf(e1.z); ef[7]=f2bf(e1.w);

    int i = i0 + t;
    char* buf = wbase + ((t & 1) << 12);
    const float* ap = Aib + (size_t)i * DD + 4 * g;

    // GEMM1 half 0: n = 0..3
    #pragma unroll
    for (int n = 0; n < 4; ++n) {
      float4 av = *(const float4*)(ap + 16 * n);
      f32x4 ci;
      ci[0] = av.x + bjv[n].x; ci[1] = av.y + bjv[n].y;
      ci[2] = av.z + bjv[n].z; ci[3] = av.w + bjv[n].w;
      f32x4 acc = __builtin_amdgcn_mfma_f32_16x16x32_bf16(weF[n], ef, ci, 0, 0, 0);
      short4v pk;
      pk[0] = f2bf(fmaxf(acc[0], 0.f)); pk[1] = f2bf(fmaxf(acc[1], 0.f));
      pk[2] = f2bf(fmaxf(acc[2], 0.f)); pk[3] = f2bf(fmaxf(acc[3], 0.f));
      *(short4v*)(buf + (((n >> 1) << 10) + ((n & 1) << 9) + wroff)) = pk;
    }
    // GEMM1 half 1: n = 4..7
    #pragma unroll
    for (int n = 4; n < 8; ++n) {
      float4 av = *(const float4*)(ap + 16 * n);
      f32x4 ci;
      ci[0] = av.x + bjv[n].x; ci[1] = av.y + bjv[n].y;
      ci[2] = av.z + bjv[n].z; ci[3] = av.w + bjv[n].w;
      f32x4 acc = __builtin_amdgcn_mfma_f32_16x16x32_bf16(weF[n], ef, ci, 0, 0, 0);
      short4v pk;
      pk[0] = f2bf(fmaxf(acc[0], 0.f)); pk[1] = f2bf(fmaxf(acc[1], 0.f));
      pk[2] = f2bf(fmaxf(acc[2], 0.f)); pk[3] = f2bf(fmaxf(acc[3], 0.f));
      *(short4v*)(buf + (((n >> 1) << 10) + ((n & 1) << 9) + wroff)) = pk;
    }

    // GEMM2: acc2[r] over kk; reads are lane-linear (conflict-free)
    f32x4 acc2;
    acc2[0] = bc2v.x; acc2[1] = bc2v.y; acc2[2] = bc2v.z; acc2[3] = bc2v.w;
    #pragma unroll
    for (int kk = 0; kk < 4; ++kk) {
      short8v pb = *(short8v*)(buf + ((kk << 10) + rdoff));
      acc2 = __builtin_amdgcn_mfma_f32_16x16x32_bf16(wcF[kk], pb, acc2, 0, 0, 0);
    }
    bool diag = (j == i);
    float4 o;
    o.x = diag ? 0.f : acc2[0];
    o.y = diag ? 0.f : acc2[1];
    o.z = diag ? 0.f : acc2[2];
    o.w = diag ? 0.f : acc2[3];
    *(float4*)(out + ((size_t)i * NN + j) * NR + 4 * g) = o;
  }
}

extern "C" void kernel_launch(void* const* d_in, const int* in_sizes, int n_in,
                              void* d_out, int out_size, void* d_ws, size_t ws_size,
                              hipStream_t stream) {
  const float* node_feat = (const float*)d_in[0];
  const float* edge_feat = (const float*)d_in[1];
  const float* adj  = (const float*)d_in[2];
  const float* W_g1 = (const float*)d_in[3];
  const float* b_g1 = (const float*)d_in[4];
  const float* W_g2 = (const float*)d_in[5];
  const float* b_g2 = (const float*)d_in[6];
  const float* W_c1 = (const float*)d_in[7];
  const float* b_c1 = (const float*)d_in[8];
  const float* W_c2 = (const float*)d_in[9];
  const float* b_c2 = (const float*)d_in[10];
  float* out = (float*)d_out;

  float* ws    = (float*)d_ws;
  float* rsinv = ws;                        // 1024
  float* part  = ws + 1024;                 // 8*1024*128 = 1048576
  float* h1    = part + 8 * NN * DD;        // 131072
  float* h2    = h1 + NN * DD;              // 131072
  float* Aib   = h2 + NN * DD;              // 131072
  float* Bmat  = Aib + NN * DD;             // 131072   (total ~6.3 MB)

  k_rowsum<<<NN, 256, 0, stream>>>(adj, rsinv);
  // layer 1
  k_adjgemm<<<512, 256, 0, stream>>>(adj, node_feat, part);
  k_dense2f<<<512, 256, 0, stream>>>(node_feat, part, rsinv, W_g1, b_g1, h1);
  // layer 2
  k_adjgemm<<<512, 256, 0, stream>>>(adj, h1, part);
  k_dense2f<<<512, 256, 0, stream>>>(h1, part, rsinv, W_g2, b_g2, h2);
  // head precompute
  k_ab<<<512, 256, 0, stream>>>(h2, W_c1, b_c1, Aib, Bmat);
  // fused edge stage: 2048 blocks x 4 waves; wave = 16 j x 8 i
  k_edge<<<2048, 256, 0, stream>>>(edge_feat, W_c1, W_c2, b_c2, Aib, Bmat, out);
}

// Round 5
// 134.470 us; speedup vs baseline: 1.5719x; 1.1521x over previous
//
#include <hip/hip_runtime.h>
#include <hip/hip_bf16.h>
#include <stdint.h>

constexpr int NN = 1024;   // nodes
constexpr int DD = 128;    // NODE_DIM == HID
constexpr int EDIM = 32;   // EDGE_DIM
constexpr int NR = 16;     // NREL

using short4v = __attribute__((ext_vector_type(4))) short;
using short8v = __attribute__((ext_vector_type(8))) short;
using f32x4   = __attribute__((ext_vector_type(4))) float;

__device__ __forceinline__ short f2bf(float x) {
  __hip_bfloat16 h = __float2bfloat16(x);   // RNE
  return __builtin_bit_cast(short, h);
}

// async global->LDS, 16B per lane. LDS dest = uniform base + lane*16 (m104);
// global src is per-lane. Low 32 bits of a generic LDS pointer are the offset.
__device__ __forceinline__ void gl_lds16(const void* g, void* l) {
  __builtin_amdgcn_global_load_lds(
      (const __attribute__((address_space(1))) unsigned int*)(uintptr_t)g,
      (__attribute__((address_space(3))) unsigned int*)(uint32_t)(uintptr_t)l,
      16, 0, 0);
}

// ---------------- K1: rsinv[i] = 1/(rowsum(adj[i]) + 1e-6) ----------------
__global__ __launch_bounds__(256) void k_rowsum(const float* __restrict__ adj,
                                                float* __restrict__ rsinv) {
  int i = blockIdx.x, t = threadIdx.x;
  const float4* row = (const float4*)(adj + (size_t)i * NN);
  float4 v = row[t];
  float s = v.x + v.y + v.z + v.w;
  #pragma unroll
  for (int off = 32; off > 0; off >>= 1) s += __shfl_down(s, off, 64);
  __shared__ float red[4];
  if ((t & 63) == 0) red[t >> 6] = s;
  __syncthreads();
  if (t == 0) rsinv[i] = 1.0f / (red[0] + red[1] + red[2] + red[3] + 1e-6f);
}

// ---------------- K2a: partial[kc][i][h] ----------------
__global__ __launch_bounds__(256) void k_adjgemm(const float* __restrict__ adj,
                                                 const float* __restrict__ X,
                                                 float* __restrict__ part) {
  __shared__ float sadj[16][128];
  int t = threadIdx.x;
  int ic = blockIdx.x & 63, kc = blockIdx.x >> 6;
  int i0 = ic * 16, k0 = kc * 128;
  {
    int il = t >> 4;
    int kl = (t & 15) * 8;
    const float4* src = (const float4*)(adj + (size_t)(i0 + il) * NN + k0 + kl);
    *(float4*)&sadj[il][kl]     = src[0];
    *(float4*)&sadj[il][kl + 4] = src[1];
  }
  __syncthreads();
  int h = t & 127, ii = t >> 7;
  float acc[8] = {0,0,0,0,0,0,0,0};
  for (int k = 0; k < 128; k += 4) {
    float x0 = X[(size_t)(k0 + k) * DD + h];
    float x1 = X[(size_t)(k0 + k + 1) * DD + h];
    float x2 = X[(size_t)(k0 + k + 2) * DD + h];
    float x3 = X[(size_t)(k0 + k + 3) * DD + h];
    #pragma unroll
    for (int m = 0; m < 8; ++m) {
      int il = ii + m * 2;
      float4 a = *(const float4*)&sadj[il][k];
      acc[m] += a.x * x0 + a.y * x1 + a.z * x2 + a.w * x3;
    }
  }
  #pragma unroll
  for (int m = 0; m < 8; ++m)
    part[((size_t)kc * NN + (i0 + ii + m * 2)) * DD + h] = acc[m];
}

// ---------------- K3/K5 (fused aggfin+dense) ----------------
__global__ __launch_bounds__(256) void k_dense2f(const float* __restrict__ X,
                                                 const float* __restrict__ part,
                                                 const float* __restrict__ rsinv,
                                                 const float* __restrict__ W,
                                                 const float* __restrict__ b,
                                                 float* __restrict__ out) {
  __shared__ float sagg[2][128];
  int t = threadIdx.x;
  int ig = t >> 7, h = t & 127;
  int i = blockIdx.x * 2 + ig;
  {
    float s = 0.f;
    #pragma unroll
    for (int kc = 0; kc < 8; ++kc) s += part[(size_t)kc * NN * DD + (size_t)i * DD + h];
    sagg[ig][h] = s * rsinv[i];
  }
  __syncthreads();
  const float4* xr = (const float4*)(X + (size_t)i * DD);
  const float4* ar = (const float4*)(&sagg[ig][0]);
  const float4* w1 = (const float4*)(W + (size_t)h * 256);
  const float4* w2 = (const float4*)(W + (size_t)h * 256 + DD);
  float acc = b[h];
  #pragma unroll 8
  for (int k = 0; k < 32; ++k) {
    float4 x = xr[k], w = w1[k];
    acc += x.x * w.x + x.y * w.y + x.z * w.z + x.w * w.w;
  }
  #pragma unroll 8
  for (int k = 0; k < 32; ++k) {
    float4 y = ar[k], w = w2[k];
    acc += y.x * w.x + y.y * w.y + y.z * w.z + y.w * w.w;
  }
  out[(size_t)i * DD + h] = fmaxf(acc, 0.f);
}

// ---------------- K6: Aib/Bmat precompute ----------------
__global__ __launch_bounds__(256) void k_ab(const float* __restrict__ h2,
                                            const float* __restrict__ Wc1,
                                            const float* __restrict__ bc1,
                                            float* __restrict__ Aib,
                                            float* __restrict__ Bmat) {
  int t = threadIdx.x;
  int i = blockIdx.x * 2 + (t >> 7), h = t & 127;
  const float4* xr = (const float4*)(h2 + (size_t)i * DD);
  const float4* wa = (const float4*)(Wc1 + (size_t)h * 288);
  const float4* wb = (const float4*)(Wc1 + (size_t)h * 288 + 128);
  float aa = bc1[h], bb = 0.f;
  #pragma unroll 8
  for (int k = 0; k < 32; ++k) {
    float4 x = xr[k];
    float4 a = wa[k], b2 = wb[k];
    aa += x.x * a.x + x.y * a.y + x.z * a.z + x.w * a.w;
    bb += x.x * b2.x + x.y * b2.y + x.z * b2.z + x.w * b2.w;
  }
  Aib[(size_t)i * DD + h] = aa;
  Bmat[(size_t)i * DD + h] = bb;
}

// ---------------- K7: fused edge stage (v5: glds pipeline, PINNED VMEM order) -----
// Block: 16 i (ig) x 64 j (jg); wave w: j = jg*64 + w*16 + c, bodies t=0..15 -> i0+t.
// Per body the VMEM issue order is pinned by empty memory-clobber asm fences:
//   [wait vmcnt(N)] [ds_read edge] |fence| [glds x2 tile t+2] |fence| [MFMA.. store]
// With that order the ledger is exact: stores 1/body, glds 2/body ->
//   body0 vmcnt(2), body1 vmcnt(3), steady vmcnt(4)  (never 0: loads span bodies).
// Source-side XOR swizzle involution: LDS[X] = tile[X ^ (((X>>7)&7)<<4)].

#define EDGE_BODY(T, SLOT, VMN) do {                                          \
    asm volatile("s_waitcnt vmcnt(" #VMN ")" ::: "memory");                   \
    char* ebuf_ = (SLOT) ? esw1 : esw0;                                       \
    float4 e0_ = *(const float4*)(ebuf_ + rd0);                               \
    float4 e1_ = *(const float4*)(ebuf_ + rd1);                               \
    asm volatile("" ::: "memory");  /* pin ds_read(edge) before glds */       \
    { int tpf_ = (T) + 2 > 15 ? 15 : (T) + 2;                                 \
      const char* src_ = ebl + (size_t)tpf_ * 131072;                         \
      gl_lds16(src_, ebuf_);                                                  \
      gl_lds16(src_ + 1024, ebuf_ + 1024); }                                  \
    asm volatile("" ::: "memory");  /* pin glds before P-tile ds ops/store */ \
    short8v ef_;                                                              \
    ef_[0]=f2bf(e0_.x); ef_[1]=f2bf(e0_.y); ef_[2]=f2bf(e0_.z); ef_[3]=f2bf(e0_.w); \
    ef_[4]=f2bf(e1_.x); ef_[5]=f2bf(e1_.y); ef_[6]=f2bf(e1_.z); ef_[7]=f2bf(e1_.w); \
    int i_ = i0 + (T);                                                        \
    const float* ap_ = aibs + (T) * 128 + 4 * g;                              \
    _Pragma("unroll")                                                         \
    for (int n = 0; n < 8; ++n) {                                             \
      float4 av_ = *(const float4*)(ap_ + 16 * n);                            \
      f32x4 ci_;                                                              \
      ci_[0] = av_.x + bjv[n].x; ci_[1] = av_.y + bjv[n].y;                   \
      ci_[2] = av_.z + bjv[n].z; ci_[3] = av_.w + bjv[n].w;                   \
      f32x4 acc_ = __builtin_amdgcn_mfma_f32_16x16x32_bf16(weF[n], ef_, ci_, 0, 0, 0); \
      short4v pk_;                                                            \
      pk_[0] = f2bf(fmaxf(acc_[0], 0.f)); pk_[1] = f2bf(fmaxf(acc_[1], 0.f)); \
      pk_[2] = f2bf(fmaxf(acc_[2], 0.f)); pk_[3] = f2bf(fmaxf(acc_[3], 0.f)); \
      *(short4v*)(psm + (((n >> 1) << 10) + ((n & 1) << 9) + wroff)) = pk_;   \
    }                                                                         \
    f32x4 acc2_;                                                              \
    acc2_[0] = bc2v.x; acc2_[1] = bc2v.y; acc2_[2] = bc2v.z; acc2_[3] = bc2v.w; \
    _Pragma("unroll")                                                         \
    for (int kk = 0; kk < 4; ++kk) {                                          \
      short8v pb_ = *(short8v*)(psm + ((kk << 10) + rdP));                    \
      acc2_ = __builtin_amdgcn_mfma_f32_16x16x32_bf16(wcF[kk], pb_, acc2_, 0, 0, 0); \
    }                                                                         \
    bool diag_ = (j == i_);                                                   \
    float4 o_;                                                                \
    o_.x = diag_ ? 0.f : acc2_[0];                                            \
    o_.y = diag_ ? 0.f : acc2_[1];                                            \
    o_.z = diag_ ? 0.f : acc2_[2];                                            \
    o_.w = diag_ ? 0.f : acc2_[3];                                            \
    *(float4*)(out + ((size_t)i_ * NN + j) * NR + 4 * g) = o_;                \
  } while (0)

__global__ __launch_bounds__(256, 3) void k_edge(const float* __restrict__ edge,
                                                 const float* __restrict__ Wc1,
                                                 const float* __restrict__ Wc2,
                                                 const float* __restrict__ bc2,
                                                 const float* __restrict__ Aib,
                                                 const float* __restrict__ Bmat,
                                                 float* __restrict__ out) {
  __shared__ __align__(16) char esm[4][2][2048];    // 16 KB edge ring (per wave x 2 slots)
  __shared__ __align__(16) char psm_all[4][4096];   // 16 KB P tiles
  __shared__ __align__(16) float aibs[16 * 128];    // 8 KB Aib panel
  int tid = threadIdx.x;
  int w = tid >> 6, lane = tid & 63;
  int c = lane & 15, g = lane >> 4;
  int ig = blockIdx.x >> 4, jg = blockIdx.x & 15;
  int i0 = ig * 16;
  int j0w = jg * 64 + w * 16;
  int j = j0w + c;

  // stage Aib panel (16 i x 128 h) into LDS; only barrier in the kernel
  {
    int ii = tid >> 4, h8 = (tid & 15) * 8;
    const float4* s = (const float4*)(Aib + (size_t)(i0 + ii) * DD + h8);
    *(float4*)(aibs + ii * 128 + h8)     = s[0];
    *(float4*)(aibs + ii * 128 + h8 + 4) = s[1];
  }
  __syncthreads();

  // We fragments: A1[m=c][k=8g+jj] = Wc1[16n+c][256+8g+jj]
  short8v weF[8];
  #pragma unroll
  for (int n = 0; n < 8; ++n) {
    const float* p = Wc1 + (size_t)(16 * n + c) * 288 + 256 + 8 * g;
    float4 f0 = *(const float4*)p;
    float4 f1 = *(const float4*)(p + 4);
    short8v s;
    s[0]=f2bf(f0.x); s[1]=f2bf(f0.y); s[2]=f2bf(f0.z); s[3]=f2bf(f0.w);
    s[4]=f2bf(f1.x); s[5]=f2bf(f1.y); s[6]=f2bf(f1.z); s[7]=f2bf(f1.w);
    weF[n] = s;
  }
  // Wc2 fragments: A2[m=c][k=32kk+8g+jj]
  short8v wcF[4];
  #pragma unroll
  for (int kk = 0; kk < 4; ++kk) {
    const float* p = Wc2 + (size_t)c * DD + 32 * kk + 8 * g;
    float4 f0 = *(const float4*)p;
    float4 f1 = *(const float4*)(p + 4);
    short8v s;
    s[0]=f2bf(f0.x); s[1]=f2bf(f0.y); s[2]=f2bf(f0.z); s[3]=f2bf(f0.w);
    s[4]=f2bf(f1.x); s[5]=f2bf(f1.y); s[6]=f2bf(f1.z); s[7]=f2bf(f1.w);
    wcF[kk] = s;
  }
  float4 bc2v = *(const float4*)(bc2 + 4 * g);
  // Bmat for this lane's j, reused across all 16 i's
  float4 bjv[8];
  #pragma unroll
  for (int n = 0; n < 8; ++n)
    bjv[n] = *(const float4*)(Bmat + (size_t)j * DD + 16 * n + 4 * g);

  char* esw0 = &esm[w][0][0];
  char* esw1 = &esm[w][1][0];
  char* psm  = &psm_all[w][0];
  // per-lane swizzled source offset within a tile (involution on bits 4-6)
  const char* ebl = (const char*)edge + ((size_t)i0 * NN + j0w) * (EDIM * 4)
                    + ((lane * 16) ^ (((lane >> 3) & 7) << 4));
  // LDS read addrs for this lane's edge slice (same involution)
  int rd0 = c * 128 + ((g * 32)      ^ ((c & 7) << 4));
  int rd1 = c * 128 + ((g * 32 + 16) ^ ((c & 7) << 4));
  // P-tile write/read offsets (v3 derived conflict-free transpose layout)
  int wroff = (c << 4) + ((g & 1) << 3) + ((g >> 1) << 8);
  int rdP   = (g << 8) + (c << 4);

  // prologue: stage tiles 0 and 1 (order pinned against later ops by the
  // wait-asm at the top of body 0)
  gl_lds16(ebl,                  esw0);
  gl_lds16(ebl + 1024,           esw0 + 1024);
  gl_lds16(ebl + 131072,         esw1);
  gl_lds16(ebl + 131072 + 1024,  esw1 + 1024);

  EDGE_BODY(0, 0, 2);
  EDGE_BODY(1, 1, 3);
  #pragma unroll 1
  for (int t = 2; t < 16; t += 2) {
    EDGE_BODY(t,     0, 4);
    EDGE_BODY(t + 1, 1, 4);
  }
}

extern "C" void kernel_launch(void* const* d_in, const int* in_sizes, int n_in,
                              void* d_out, int out_size, void* d_ws, size_t ws_size,
                              hipStream_t stream) {
  const float* node_feat = (const float*)d_in[0];
  const float* edge_feat = (const float*)d_in[1];
  const float* adj  = (const float*)d_in[2];
  const float* W_g1 = (const float*)d_in[3];
  const float* b_g1 = (const float*)d_in[4];
  const float* W_g2 = (const float*)d_in[5];
  const float* b_g2 = (const float*)d_in[6];
  const float* W_c1 = (const float*)d_in[7];
  const float* b_c1 = (const float*)d_in[8];
  const float* W_c2 = (const float*)d_in[9];
  const float* b_c2 = (const float*)d_in[10];
  float* out = (float*)d_out;

  float* ws    = (float*)d_ws;
  float* rsinv = ws;                        // 1024
  float* part  = ws + 1024;                 // 8*1024*128
  float* h1    = part + 8 * NN * DD;        // 131072
  float* h2    = h1 + NN * DD;              // 131072
  float* Aib   = h2 + NN * DD;              // 131072
  float* Bmat  = Aib + NN * DD;             // 131072

  k_rowsum<<<NN, 256, 0, stream>>>(adj, rsinv);
  // layer 1
  k_adjgemm<<<512, 256, 0, stream>>>(adj, node_feat, part);
  k_dense2f<<<512, 256, 0, stream>>>(node_feat, part, rsinv, W_g1, b_g1, h1);
  // layer 2
  k_adjgemm<<<512, 256, 0, stream>>>(adj, h1, part);
  k_dense2f<<<512, 256, 0, stream>>>(h1, part, rsinv, W_g2, b_g2, h2);
  // head precompute
  k_ab<<<512, 256, 0, stream>>>(h2, W_c1, b_c1, Aib, Bmat);
  // fused edge stage: 1024 blocks x 4 waves; wave = 16 j x 16 i
  k_edge<<<1024, 256, 0, stream>>>(edge_feat, W_c1, W_c2, b_c2, Aib, Bmat, out);
}